// Round 11
// baseline (358.589 us; speedup 1.0000x reference)
//
#include <hip/hip_runtime.h>
#include <stdint.h>

// MultiHeadAttentionShuffle: BS=4, SL=128, D=512, H=8, DP=64
// attn[b,t,h,q,k] = E[iq,ik[k]] * F[t,iq]  (iq=idx_q[t,q]) for q<=t,k<=t;
//                 = 1/(t+1) for q>t,k<=t; 0 for k>t.
// R17 == R16 with compile fix (local float4 regs renamed areg/wreg: the
// inlined proj body's local `wv` collided with the parameter `wv`):
//   (a) proj: 2-way K-split (768 blocks, 16 serial K-iters instead of 32),
//       partials atomicAdd onto bias-pre-initialized qp/kp/vp.
//   (b) init kernel: out=db AND qp/kp/vp=bias in one launch.
//   attn/sef/idx = R14 (best, 352.2us).

#define BSZ 4
#define SLEN 128
#define DMODEL 512
#define NHEAD 8
#define HDIM 64

typedef float f32x4_t __attribute__((ext_vector_type(4)));

__device__ __forceinline__ uint32_t rotl32(uint32_t v, int d) {
  return (v << d) | (v >> (32 - d));
}

__device__ __forceinline__ void tf2x32(uint32_t k0, uint32_t k1, uint32_t x0,
                                       uint32_t x1, uint32_t& y0, uint32_t& y1) {
  uint32_t ks2 = k0 ^ k1 ^ 0x1BD11BDAu;
  x0 += k0; x1 += k1;
#define TF_R(r) { x0 += x1; x1 = rotl32(x1, (r)); x1 ^= x0; }
  TF_R(13) TF_R(15) TF_R(26) TF_R(6)
  x0 += k1;  x1 += ks2 + 1u;
  TF_R(17) TF_R(29) TF_R(16) TF_R(24)
  x0 += ks2; x1 += k0 + 2u;
  TF_R(13) TF_R(15) TF_R(26) TF_R(6)
  x0 += k0;  x1 += k1 + 3u;
  TF_R(17) TF_R(29) TF_R(16) TF_R(24)
  x0 += k1;  x1 += ks2 + 4u;
  TF_R(13) TF_R(15) TF_R(26) TF_R(6)
  x0 += ks2; x1 += k0 + 5u;
#undef TF_R
  y0 = x0; y1 = x1;
}

__device__ __forceinline__ uint16_t f32_to_bf16(float v) {
  uint32_t x = __float_as_uint(v);
  return (uint16_t)((x + 0x7FFFu + ((x >> 16) & 1u)) >> 16);
}
__device__ __forceinline__ float bf16_to_f32(uint16_t b) {
  return __uint_as_float(((uint32_t)b) << 16);
}

// ---- init: out[b,t,:]=db, qp/kp/vp[b,t,:]=bq/bk/bv (proj atomically adds) ----
__global__ __launch_bounds__(512) void init_kernel(float* __restrict__ out,
                                                   float* __restrict__ qp,
                                                   float* __restrict__ kp,
                                                   float* __restrict__ vp,
                                                   const float* __restrict__ db,
                                                   const float* __restrict__ bq,
                                                   const float* __restrict__ bk,
                                                   const float* __restrict__ bv) {
  const int i = blockIdx.x * 512 + threadIdx.x;   // 0 .. 4*262144-1
  const int region = i >> 18;                      // 262144 = 2^18
  const int off = i & 0x3FFFF;
  const int c = off & (DMODEL - 1);
  if (region == 0)      out[off] = db[c];
  else if (region == 1) qp[off] = bq[c];
  else if (region == 2) kp[off] = bk[c];
  else                  vp[off] = bv[c];
}

// ---------------- permutation indices (jax threefry partitionable) ----------------
__global__ __launch_bounds__(128) void idx_kernel(int* __restrict__ idx) {
  const int m = blockIdx.x;   // 0=q,1=k,2=v
  const int t = blockIdx.y;
  const int j = threadIdx.x;
  __shared__ float u[SLEN];
  uint32_t fk0, fk1;
  tf2x32(0u, 42u, 0u, (uint32_t)m, fk0, fk1);
  const int flat = t * SLEN + j;
  uint32_t y0, y1;
  tf2x32(fk0, fk1, 0u, (uint32_t)flat, y0, y1);
  uint32_t bits = y0 ^ y1;
  float uu = __uint_as_float((bits >> 9) | 0x3f800000u) - 1.0f;
  u[j] = uu;
  __syncthreads();
  int* row = idx + (m * SLEN + t) * SLEN;
  if (j >= t) {
    row[j] = j;
  } else {
    int rank = 0;
    for (int i = 0; i < t; ++i) {
      float ui = u[i];
      rank += ((ui < uu) || (ui == uu && i < j)) ? 1 : 0;
    }
    row[rank] = j;  // stable argsort
  }
}

// -- 512-col GEMM, 2-way K-split: 32x64 tile, 16 K-iters, atomicAdd partials --
__global__ __launch_bounds__(256) void proj_kernel(
    const float* __restrict__ q, const float* __restrict__ k, const float* __restrict__ v,
    const float* __restrict__ wq, const float* __restrict__ wk, const float* __restrict__ wv,
    float* __restrict__ qp, float* __restrict__ kp, float* __restrict__ vp) {
  __shared__ float As[32 * 17];
  __shared__ float Ws[16 * 64];
  const int which = blockIdx.z % 3;
  const int kbase = (blockIdx.z / 3) * 256;
  const float* A; const float* W; float* C;
  if (which == 0)      { A = q; W = wq; C = qp; }
  else if (which == 1) { A = k; W = wk; C = kp; }
  else                 { A = v; W = wv; C = vp; }
  const int tid = threadIdx.x;
  const int tx = tid & 15;           // col group (4 cols)
  const int ty = tid >> 4;           // 0..15 -> rows ty*2, ty*2+1
  const int row0 = blockIdx.y * 32, col0 = blockIdx.x * 64;
  const int lr = tid >> 2, lc = (tid & 3) << 2;   // A-tile loads (32x16), tid<128
  const int wr = tid >> 4, wc = (tid & 15) << 2;  // W-tile loads (16x64), all thr
  float acc[2][4] = {};
  float4 areg, wreg;
  if (tid < 128) areg = *(const float4*)(A + (size_t)(row0 + lr) * 512 + kbase + lc);
  wreg = *(const float4*)(W + (size_t)(kbase + wr) * 512 + col0 + wc);
  for (int k0 = 0; k0 < 256; k0 += 16) {
    if (tid < 128) {
      As[lr * 17 + lc + 0] = areg.x; As[lr * 17 + lc + 1] = areg.y;
      As[lr * 17 + lc + 2] = areg.z; As[lr * 17 + lc + 3] = areg.w;
    }
    *(float4*)(Ws + wr * 64 + wc) = wreg;
    __syncthreads();
    if (k0 + 16 < 256) {  // prefetch next slab into registers during compute
      if (tid < 128)
        areg = *(const float4*)(A + (size_t)(row0 + lr) * 512 + kbase + k0 + 16 + lc);
      wreg = *(const float4*)(W + (size_t)(kbase + k0 + 16 + wr) * 512 + col0 + wc);
    }
#pragma unroll
    for (int kk = 0; kk < 16; ++kk) {
      float a0 = As[(ty * 2 + 0) * 17 + kk];
      float a1 = As[(ty * 2 + 1) * 17 + kk];
      float bvv[4];
#pragma unroll
      for (int jj = 0; jj < 4; ++jj) bvv[jj] = Ws[kk * 64 + tx * 4 + jj];
#pragma unroll
      for (int jj = 0; jj < 4; ++jj) {
        acc[0][jj] += a0 * bvv[jj];
        acc[1][jj] += a1 * bvv[jj];
      }
    }
    __syncthreads();
  }
#pragma unroll
  for (int i = 0; i < 2; ++i) {
    int r = row0 + ty * 2 + i, c = col0 + tx * 4;
    float* crow = C + (size_t)r * 512 + c;
#pragma unroll
    for (int jj = 0; jj < 4; ++jj) atomicAdd(crow + jj, acc[i][jj]);
  }
}

// ------- fused S + softmax factors, 4-way q-row split: E (bf16) and F -------
// grid (8 h, 4 b, 4 qc); block 256. Each block: q-rows qc*32..qc*32+31, all 128 k.
__global__ __launch_bounds__(256) void sef_kernel(const float* __restrict__ qp,
                                                  const float* __restrict__ kp,
                                                  uint16_t* __restrict__ E,
                                                  float* __restrict__ Ft) {
  const int h = blockIdx.x, b = blockIdx.y, qc = blockIdx.z;
  const int tid = threadIdx.x;
  __shared__ float qs[32 * 36];      // [d][qrow 32+pad]
  __shared__ float ks[32 * 132];     // [d][krow 128+pad]
  __shared__ float redm[32 * 16];    // per (row, jgroup) partial max
  __shared__ float csum[32 * 16];    // per (row, jgroup) exp-sum
  __shared__ float m32s[32];
  const float* qbase = qp + ((size_t)(b * SLEN + qc * 32)) * DMODEL + h * HDIM;
  const float* kbase = kp + ((size_t)b * SLEN) * DMODEL + h * HDIM;
  const int i0 = (tid >> 4) * 2, jg = tid & 15, j0 = jg * 8;
  float acc[2][8] = {};
  for (int d0 = 0; d0 < HDIM; d0 += 32) {
    __syncthreads();
    {  // q tile: 32 rows x 32 d = 256 float4, 1/thread
      int row = tid >> 3, c4 = (tid & 7) << 2;
      float4 a = *(const float4*)(qbase + (size_t)row * DMODEL + d0 + c4);
      qs[(c4 + 0) * 36 + row] = a.x; qs[(c4 + 1) * 36 + row] = a.y;
      qs[(c4 + 2) * 36 + row] = a.z; qs[(c4 + 3) * 36 + row] = a.w;
    }
    for (int it = 0; it < 4; ++it) {  // k tile: 128 rows x 32 d = 1024 float4
      int flat = it * 256 + tid;
      int row = flat >> 3, c4 = (flat & 7) << 2;
      float4 bb = *(const float4*)(kbase + (size_t)row * DMODEL + d0 + c4);
      ks[(c4 + 0) * 132 + row] = bb.x; ks[(c4 + 1) * 132 + row] = bb.y;
      ks[(c4 + 2) * 132 + row] = bb.z; ks[(c4 + 3) * 132 + row] = bb.w;
    }
    __syncthreads();
    for (int d = 0; d < 32; ++d) {
      float a0 = qs[d * 36 + i0 + 0];
      float a1 = qs[d * 36 + i0 + 1];
      float4 ka = *(const float4*)(ks + d * 132 + j0);
      float4 kb = *(const float4*)(ks + d * 132 + j0 + 4);
      float bb[8] = {ka.x, ka.y, ka.z, ka.w, kb.x, kb.y, kb.z, kb.w};
#pragma unroll
      for (int c = 0; c < 8; ++c) {
        acc[0][c] += a0 * bb[c];
        acc[1][c] += a1 * bb[c];
      }
    }
  }
#pragma unroll
  for (int r = 0; r < 2; ++r) {
    float m = -3.402823466e38f;
#pragma unroll
    for (int c = 0; c < 8; ++c) {
      acc[r][c] *= 0.125f;
      m = fmaxf(m, acc[r][c]);
    }
    redm[(i0 + r) * 16 + jg] = m;
  }
  __syncthreads();
  if (tid < 32) {
    float m = redm[tid * 16];
#pragma unroll
    for (int g = 1; g < 16; ++g) m = fmaxf(m, redm[tid * 16 + g]);
    m32s[tid] = m;
  }
  __syncthreads();
  const int bh = b * NHEAD + h;
  uint16_t* Eb = E + (size_t)bh * SLEN * SLEN;
#pragma unroll
  for (int r = 0; r < 2; ++r) {
    const int grow = qc * 32 + i0 + r;
    const float m = m32s[i0 + r];
    float run = 0.f;
    ushort4 e0, e1;
    float ev;
    ev = __expf(acc[r][0] - m); e0.x = f32_to_bf16(ev); run += ev; acc[r][0] = run;
    ev = __expf(acc[r][1] - m); e0.y = f32_to_bf16(ev); run += ev; acc[r][1] = run;
    ev = __expf(acc[r][2] - m); e0.z = f32_to_bf16(ev); run += ev; acc[r][2] = run;
    ev = __expf(acc[r][3] - m); e0.w = f32_to_bf16(ev); run += ev; acc[r][3] = run;
    ev = __expf(acc[r][4] - m); e1.x = f32_to_bf16(ev); run += ev; acc[r][4] = run;
    ev = __expf(acc[r][5] - m); e1.y = f32_to_bf16(ev); run += ev; acc[r][5] = run;
    ev = __expf(acc[r][6] - m); e1.z = f32_to_bf16(ev); run += ev; acc[r][6] = run;
    ev = __expf(acc[r][7] - m); e1.w = f32_to_bf16(ev); run += ev; acc[r][7] = run;
    *(ushort4*)(Eb + (size_t)grow * SLEN + j0) = e0;
    *(ushort4*)(Eb + (size_t)grow * SLEN + j0 + 4) = e1;
    csum[(i0 + r) * 16 + jg] = run;
  }
  __syncthreads();
  float* Fb = Ft + (size_t)bh * SLEN * SLEN;
#pragma unroll
  for (int r = 0; r < 2; ++r) {
    const int grow = qc * 32 + i0 + r;
    float base = 0.f;
    for (int g = 0; g < 16; ++g) {
      if (g == jg) break;
      base += csum[(i0 + r) * 16 + g];
    }
#pragma unroll
    for (int c = 0; c < 8; ++c)
      Fb[(size_t)(j0 + c) * SLEN + grow] = 1.0f / (base + acc[r][c]);
  }
}

// --- attn writer (8 t/block, LDS E) + amortized fused dense partial-GEMV ---
__global__ __launch_bounds__(256) void attn_kernel(const uint16_t* __restrict__ E,
                                                   const float* __restrict__ Ft,
                                                   const int* __restrict__ idx,
                                                   const float* __restrict__ vp,
                                                   const float* __restrict__ dw,
                                                   float* __restrict__ attn_out,
                                                   float* __restrict__ out) {
  const int h = blockIdx.x;     // 8
  const int tg = blockIdx.y;    // 16 (8 t each)
  const int b = blockIdx.z;     // 4
  const int tid = threadIdx.x;
  const int wave = tid >> 6, lane = tid & 63;
  const int half = lane >> 5, l32 = lane & 31;
  const int bh = b * NHEAD + h;
  __shared__ __align__(16) uint16_t Es[SLEN * SLEN];  // 32 KB: full E tile for (b,h)
  __shared__ int iqs[8][SLEN];
  __shared__ int iks[8][SLEN];
  __shared__ int ivs[8][SLEN];
  __shared__ float Fsl[8][SLEN];
  __shared__ float effs[8][HDIM];
  // stage E: 32 KB = 2048 uint4, coalesced
  {
    const uint4* src = (const uint4*)(E + (size_t)bh * SLEN * SLEN);
    uint4* dst = (uint4*)Es;
#pragma unroll
    for (int i = 0; i < 8; ++i) dst[i * 256 + tid] = src[i * 256 + tid];
  }
  // stage idx rows + F rows for the 8 t values
  {
    const int t0 = tg * 8;
#pragma unroll
    for (int ii = 0; ii < 4; ++ii) {
      int i = ii * 256 + tid;
      int s = i >> 7, j = i & 127;
      int t = t0 + s;
      iqs[s][j] = idx[(0 * SLEN + t) * SLEN + j];
      iks[s][j] = idx[(1 * SLEN + t) * SLEN + j];
      ivs[s][j] = idx[(2 * SLEN + t) * SLEN + j];
      Fsl[s][j] = Ft[((size_t)bh * SLEN + t) * SLEN + j];
    }
  }
  __syncthreads();
  const int k0 = l32 * 4;
  const int d = (wave << 4) + (lane >> 2);   // eff: d-channel for this lane
  const int kg = lane & 3;                   // eff: 4-way k split within 4 lanes
  const float* vb = vp + (size_t)b * SLEN * DMODEL + h * HDIM + d;
  for (int s = 0; s < 8; ++s) {
    const int t = tg * 8 + s;
    const int ikA = iks[s][k0], ikB = iks[s][k0 + 1], ikC = iks[s][k0 + 2], ikD = iks[s][k0 + 3];
    float4 cm;   // causal k-mask for this lane's 4 columns
    cm.x = (k0 + 0 <= t) ? 1.f : 0.f;
    cm.y = (k0 + 1 <= t) ? 1.f : 0.f;
    cm.z = (k0 + 2 <= t) ? 1.f : 0.f;
    cm.w = (k0 + 3 <= t) ? 1.f : 0.f;
    const float inv = 1.0f / (float)(t + 1);
    float* obase = attn_out + ((size_t)((b * SLEN + t) * NHEAD + h)) * SLEN * SLEN;
#pragma unroll 2
    for (int q8 = wave * 2; q8 < SLEN; q8 += 8) {
      const int qe = q8 + half;   // this half-wave's q-row
      f32x4_t val;
      if (qe <= t) {
        const int iq = iqs[s][qe];
        const float f = Fsl[s][iq];
        const uint16_t* Er = Es + iq * SLEN;
        val.x = bf16_to_f32(Er[ikA]) * f * cm.x;
        val.y = bf16_to_f32(Er[ikB]) * f * cm.y;
        val.z = bf16_to_f32(Er[ikC]) * f * cm.z;
        val.w = bf16_to_f32(Er[ikD]) * f * cm.w;
      } else {
        val.x = inv * cm.x; val.y = inv * cm.y;
        val.z = inv * cm.z; val.w = inv * cm.w;
      }
      __builtin_nontemporal_store(val, (f32x4_t*)(obase + (size_t)qe * SLEN + k0));
    }
    // effs[s][d] = F[t][t] * sum_{k<=t} E[t][ik[k]] * vp[b, iv[k], h*64+d]
    // 8-deep batched prefetch; per-lane summation order (k ascending) preserved.
    {
      const uint16_t* Et = Es + t * SLEN;
      float acc = 0.f;
      int k = kg;
      for (; k + 28 <= t; k += 32) {
        float vv[8], ee[8];
#pragma unroll
        for (int i = 0; i < 8; ++i) {
          vv[i] = vb[(size_t)ivs[s][k + 4 * i] * DMODEL];
          ee[i] = bf16_to_f32(Et[iks[s][k + 4 * i]]);
        }
#pragma unroll
        for (int i = 0; i < 8; ++i) acc += ee[i] * vv[i];
      }
      for (; k <= t; k += 4)
        acc += bf16_to_f32(Et[iks[s][k]]) * vb[(size_t)ivs[s][k] * DMODEL];
      acc += __shfl_xor(acc, 1);
      acc += __shfl_xor(acc, 2);
      if (kg == 0) effs[s][d] = acc * Fsl[s][t];
    }
  }
  __syncthreads();
  // out[b,t0+s,c] += sum_d effs[s][d] * dw[h*64+d][c]; dw slice read ONCE/block.
  {
    const int c0 = tid * 2;
    const float* wb = dw + (size_t)(h * HDIM) * DMODEL + c0;
    float s0[8] = {}, s1[8] = {};
#pragma unroll 8
    for (int dd = 0; dd < HDIM; ++dd) {
      const float2 wv2 = *(const float2*)(wb + (size_t)dd * DMODEL);
#pragma unroll
      for (int s = 0; s < 8; ++s) {
        const float e = effs[s][dd];
        s0[s] += e * wv2.x;
        s1[s] += e * wv2.y;
      }
    }
    const int t0 = tg * 8;
#pragma unroll
    for (int s = 0; s < 8; ++s) {
      float* orow = out + ((size_t)(b * SLEN + t0 + s)) * DMODEL;
      atomicAdd(orow + c0 + 0, s0[s]);
      atomicAdd(orow + c0 + 1, s1[s]);
    }
  }
}

extern "C" void kernel_launch(void* const* d_in, const int* in_sizes, int n_in,
                              void* d_out, int out_size, void* d_ws, size_t ws_size,
                              hipStream_t stream) {
  const float* q    = (const float*)d_in[0];
  const float* k    = (const float*)d_in[1];
  const float* v    = (const float*)d_in[2];
  const float* wq_w = (const float*)d_in[4];
  const float* wq_b = (const float*)d_in[5];
  const float* wk_w = (const float*)d_in[6];
  const float* wk_b = (const float*)d_in[7];
  const float* wv_w = (const float*)d_in[8];
  const float* wv_b = (const float*)d_in[9];
  const float* dw   = (const float*)d_in[10];
  const float* db   = (const float*)d_in[11];

  float* out  = (float*)d_out;          // 4*128*512
  float* attn = out + 262144;           // 4*128*8*128*128

  // ws layout (float slots): E(bf16) | idx | qp | kp | vp | Ft
  float* wsf = (float*)d_ws;
  uint16_t* E = (uint16_t*)wsf;                    // 524288 u16 in 262144 float slots
  int*   idx = (int*)(wsf + 262144);               // 49152
  float* qp  = wsf + 311296;
  float* kp  = qp + 262144;
  float* vp  = kp + 262144;
  float* Ft  = vp + 262144;                        // 524288
  (void)in_sizes; (void)n_in; (void)out_size; (void)ws_size;

  init_kernel<<<dim3(2048, 1, 1), 512, 0, stream>>>(out, qp, kp, vp,
                                                    db, wq_b, wk_b, wv_b);
  idx_kernel<<<dim3(3, 128, 1), 128, 0, stream>>>(idx);
  proj_kernel<<<dim3(8, 16, 6), 256, 0, stream>>>(q, k, v, wq_w, wk_w, wv_w,
                                                  qp, kp, vp);
  sef_kernel<<<dim3(8, 4, 4), 256, 0, stream>>>(qp, kp, E, Ft);
  attn_kernel<<<dim3(8, 16, 4), 256, 0, stream>>>(E, Ft, idx, vp, dw, attn, out);
}

// Round 13
// 351.893 us; speedup vs baseline: 1.0190x; 1.0190x over previous
//
#include <hip/hip_runtime.h>
#include <stdint.h>

// MultiHeadAttentionShuffle: BS=4, SL=128, D=512, H=8, DP=64
// attn[b,t,h,q,k] = E[iq,ik[k]] * F[t,iq]  (iq=idx_q[t,q]) for q<=t,k<=t;
//                 = 1/(t+1) for q>t,k<=t; 0 for k>t.
// R19 = R14 verbatim resubmitted (R18 run died on container acquisition —
// same infra failure mode as R7/R8; source identical to the verified
// 352.2 us best):
//   - proj: 32x64 tiles + register-prefetch pipeline, bias in epilogue.
//   - sef: 4-way q-row split (128 blocks), E bf16 + F factors on-chip.
//   - attn: 8 t/block, E staged in LDS, nt float4 stores, 8-deep eff
//     prefetch, fused amortized dense partial-GEMV via atomicAdd.
//   - out_init: out = dense_b.

#define BSZ 4
#define SLEN 128
#define DMODEL 512
#define NHEAD 8
#define HDIM 64

typedef float f32x4_t __attribute__((ext_vector_type(4)));

__device__ __forceinline__ uint32_t rotl32(uint32_t v, int d) {
  return (v << d) | (v >> (32 - d));
}

__device__ __forceinline__ void tf2x32(uint32_t k0, uint32_t k1, uint32_t x0,
                                       uint32_t x1, uint32_t& y0, uint32_t& y1) {
  uint32_t ks2 = k0 ^ k1 ^ 0x1BD11BDAu;
  x0 += k0; x1 += k1;
#define TF_R(r) { x0 += x1; x1 = rotl32(x1, (r)); x1 ^= x0; }
  TF_R(13) TF_R(15) TF_R(26) TF_R(6)
  x0 += k1;  x1 += ks2 + 1u;
  TF_R(17) TF_R(29) TF_R(16) TF_R(24)
  x0 += ks2; x1 += k0 + 2u;
  TF_R(13) TF_R(15) TF_R(26) TF_R(6)
  x0 += k0;  x1 += k1 + 3u;
  TF_R(17) TF_R(29) TF_R(16) TF_R(24)
  x0 += k1;  x1 += ks2 + 4u;
  TF_R(13) TF_R(15) TF_R(26) TF_R(6)
  x0 += ks2; x1 += k0 + 5u;
#undef TF_R
  y0 = x0; y1 = x1;
}

__device__ __forceinline__ uint16_t f32_to_bf16(float v) {
  uint32_t x = __float_as_uint(v);
  return (uint16_t)((x + 0x7FFFu + ((x >> 16) & 1u)) >> 16);
}
__device__ __forceinline__ float bf16_to_f32(uint16_t b) {
  return __uint_as_float(((uint32_t)b) << 16);
}

// ---------------- out init: out[b,t,c] = dense_b[c] ----------------
__global__ __launch_bounds__(512) void out_init_kernel(float* __restrict__ out,
                                                       const float* __restrict__ db) {
  const int i = blockIdx.x * 512 + threadIdx.x;
  out[i] = db[i & (DMODEL - 1)];
}

// ---------------- permutation indices (jax threefry partitionable) ----------------
__global__ __launch_bounds__(128) void idx_kernel(int* __restrict__ idx) {
  const int m = blockIdx.x;   // 0=q,1=k,2=v
  const int t = blockIdx.y;
  const int j = threadIdx.x;
  __shared__ float u[SLEN];
  uint32_t fk0, fk1;
  tf2x32(0u, 42u, 0u, (uint32_t)m, fk0, fk1);
  const int flat = t * SLEN + j;
  uint32_t y0, y1;
  tf2x32(fk0, fk1, 0u, (uint32_t)flat, y0, y1);
  uint32_t bits = y0 ^ y1;
  float uu = __uint_as_float((bits >> 9) | 0x3f800000u) - 1.0f;
  u[j] = uu;
  __syncthreads();
  int* row = idx + (m * SLEN + t) * SLEN;
  if (j >= t) {
    row[j] = j;
  } else {
    int rank = 0;
    for (int i = 0; i < t; ++i) {
      float ui = u[i];
      rank += ((ui < uu) || (ui == uu && i < j)) ? 1 : 0;
    }
    row[rank] = j;  // stable argsort
  }
}

// -------- 512-col GEMM: 32x64 tile, 256 thr, 2x4/thread, reg-prefetch pipeline --------
__device__ __forceinline__ void gemm512_body(const float* __restrict__ A,
                                             const float* __restrict__ W,
                                             const float* __restrict__ bias,
                                             float* __restrict__ C,
                                             float* As /*32*17*/, float* Ws /*16*64*/) {
  const int tid = threadIdx.x;
  const int tx = tid & 15;           // col group (4 cols)
  const int ty = tid >> 4;           // 0..15 -> rows ty*2, ty*2+1
  const int row0 = blockIdx.y * 32, col0 = blockIdx.x * 64;
  const int lr = tid >> 2, lc = (tid & 3) << 2;   // A-tile loads (32x16), tid<128
  const int wr = tid >> 4, wc = (tid & 15) << 2;  // W-tile loads (16x64), all thr
  float acc[2][4] = {};
  float4 av, wv;
  if (tid < 128) av = *(const float4*)(A + (size_t)(row0 + lr) * 512 + lc);
  wv = *(const float4*)(W + (size_t)wr * 512 + col0 + wc);
  for (int k0 = 0; k0 < 512; k0 += 16) {
    if (tid < 128) {
      As[lr * 17 + lc + 0] = av.x; As[lr * 17 + lc + 1] = av.y;
      As[lr * 17 + lc + 2] = av.z; As[lr * 17 + lc + 3] = av.w;
    }
    *(float4*)(Ws + wr * 64 + wc) = wv;
    __syncthreads();
    if (k0 + 16 < 512) {  // prefetch next slab into registers during compute
      if (tid < 128) av = *(const float4*)(A + (size_t)(row0 + lr) * 512 + k0 + 16 + lc);
      wv = *(const float4*)(W + (size_t)(k0 + 16 + wr) * 512 + col0 + wc);
    }
#pragma unroll
    for (int kk = 0; kk < 16; ++kk) {
      float a0 = As[(ty * 2 + 0) * 17 + kk];
      float a1 = As[(ty * 2 + 1) * 17 + kk];
      float bvv[4];
#pragma unroll
      for (int jj = 0; jj < 4; ++jj) bvv[jj] = Ws[kk * 64 + tx * 4 + jj];
#pragma unroll
      for (int jj = 0; jj < 4; ++jj) {
        acc[0][jj] += a0 * bvv[jj];
        acc[1][jj] += a1 * bvv[jj];
      }
    }
    __syncthreads();
  }
#pragma unroll
  for (int i = 0; i < 2; ++i) {
    int r = row0 + ty * 2 + i, c = col0 + tx * 4;
    float4 o;
    o.x = acc[i][0] + bias[c + 0];
    o.y = acc[i][1] + bias[c + 1];
    o.z = acc[i][2] + bias[c + 2];
    o.w = acc[i][3] + bias[c + 3];
    *(float4*)(C + (size_t)r * 512 + c) = o;
  }
}

__global__ __launch_bounds__(256) void proj_kernel(
    const float* __restrict__ q, const float* __restrict__ k, const float* __restrict__ v,
    const float* __restrict__ wq, const float* __restrict__ wk, const float* __restrict__ wv,
    const float* __restrict__ bq, const float* __restrict__ bk, const float* __restrict__ bv,
    float* __restrict__ qp, float* __restrict__ kp, float* __restrict__ vp) {
  __shared__ float As[32 * 17];
  __shared__ float Ws[16 * 64];
  const float* A; const float* W; const float* B; float* C;
  if (blockIdx.z == 0)      { A = q; W = wq; B = bq; C = qp; }
  else if (blockIdx.z == 1) { A = k; W = wk; B = bk; C = kp; }
  else                      { A = v; W = wv; B = bv; C = vp; }
  gemm512_body(A, W, B, C, As, Ws);
}

// ------- fused S + softmax factors, 4-way q-row split: E (bf16) and F -------
// grid (8 h, 4 b, 4 qc); block 256. Each block: q-rows qc*32..qc*32+31, all 128 k.
__global__ __launch_bounds__(256) void sef_kernel(const float* __restrict__ qp,
                                                  const float* __restrict__ kp,
                                                  uint16_t* __restrict__ E,
                                                  float* __restrict__ Ft) {
  const int h = blockIdx.x, b = blockIdx.y, qc = blockIdx.z;
  const int tid = threadIdx.x;
  __shared__ float qs[32 * 36];      // [d][qrow 32+pad]
  __shared__ float ks[32 * 132];     // [d][krow 128+pad]
  __shared__ float redm[32 * 16];    // per (row, jgroup) partial max
  __shared__ float csum[32 * 16];    // per (row, jgroup) exp-sum
  __shared__ float m32s[32];
  const float* qbase = qp + ((size_t)(b * SLEN + qc * 32)) * DMODEL + h * HDIM;
  const float* kbase = kp + ((size_t)b * SLEN) * DMODEL + h * HDIM;
  const int i0 = (tid >> 4) * 2, jg = tid & 15, j0 = jg * 8;
  float acc[2][8] = {};
  for (int d0 = 0; d0 < HDIM; d0 += 32) {
    __syncthreads();
    {  // q tile: 32 rows x 32 d = 256 float4, 1/thread
      int row = tid >> 3, c4 = (tid & 7) << 2;
      float4 a = *(const float4*)(qbase + (size_t)row * DMODEL + d0 + c4);
      qs[(c4 + 0) * 36 + row] = a.x; qs[(c4 + 1) * 36 + row] = a.y;
      qs[(c4 + 2) * 36 + row] = a.z; qs[(c4 + 3) * 36 + row] = a.w;
    }
    for (int it = 0; it < 4; ++it) {  // k tile: 128 rows x 32 d = 1024 float4
      int flat = it * 256 + tid;
      int row = flat >> 3, c4 = (flat & 7) << 2;
      float4 bb = *(const float4*)(kbase + (size_t)row * DMODEL + d0 + c4);
      ks[(c4 + 0) * 132 + row] = bb.x; ks[(c4 + 1) * 132 + row] = bb.y;
      ks[(c4 + 2) * 132 + row] = bb.z; ks[(c4 + 3) * 132 + row] = bb.w;
    }
    __syncthreads();
    for (int d = 0; d < 32; ++d) {
      float a0 = qs[d * 36 + i0 + 0];
      float a1 = qs[d * 36 + i0 + 1];
      float4 ka = *(const float4*)(ks + d * 132 + j0);
      float4 kb = *(const float4*)(ks + d * 132 + j0 + 4);
      float bb[8] = {ka.x, ka.y, ka.z, ka.w, kb.x, kb.y, kb.z, kb.w};
#pragma unroll
      for (int c = 0; c < 8; ++c) {
        acc[0][c] += a0 * bb[c];
        acc[1][c] += a1 * bb[c];
      }
    }
  }
#pragma unroll
  for (int r = 0; r < 2; ++r) {
    float m = -3.402823466e38f;
#pragma unroll
    for (int c = 0; c < 8; ++c) {
      acc[r][c] *= 0.125f;
      m = fmaxf(m, acc[r][c]);
    }
    redm[(i0 + r) * 16 + jg] = m;
  }
  __syncthreads();
  if (tid < 32) {
    float m = redm[tid * 16];
#pragma unroll
    for (int g = 1; g < 16; ++g) m = fmaxf(m, redm[tid * 16 + g]);
    m32s[tid] = m;
  }
  __syncthreads();
  const int bh = b * NHEAD + h;
  uint16_t* Eb = E + (size_t)bh * SLEN * SLEN;
#pragma unroll
  for (int r = 0; r < 2; ++r) {
    const int grow = qc * 32 + i0 + r;
    const float m = m32s[i0 + r];
    float run = 0.f;
    ushort4 e0, e1;
    float ev;
    ev = __expf(acc[r][0] - m); e0.x = f32_to_bf16(ev); run += ev; acc[r][0] = run;
    ev = __expf(acc[r][1] - m); e0.y = f32_to_bf16(ev); run += ev; acc[r][1] = run;
    ev = __expf(acc[r][2] - m); e0.z = f32_to_bf16(ev); run += ev; acc[r][2] = run;
    ev = __expf(acc[r][3] - m); e0.w = f32_to_bf16(ev); run += ev; acc[r][3] = run;
    ev = __expf(acc[r][4] - m); e1.x = f32_to_bf16(ev); run += ev; acc[r][4] = run;
    ev = __expf(acc[r][5] - m); e1.y = f32_to_bf16(ev); run += ev; acc[r][5] = run;
    ev = __expf(acc[r][6] - m); e1.z = f32_to_bf16(ev); run += ev; acc[r][6] = run;
    ev = __expf(acc[r][7] - m); e1.w = f32_to_bf16(ev); run += ev; acc[r][7] = run;
    *(ushort4*)(Eb + (size_t)grow * SLEN + j0) = e0;
    *(ushort4*)(Eb + (size_t)grow * SLEN + j0 + 4) = e1;
    csum[(i0 + r) * 16 + jg] = run;
  }
  __syncthreads();
  float* Fb = Ft + (size_t)bh * SLEN * SLEN;
#pragma unroll
  for (int r = 0; r < 2; ++r) {
    const int grow = qc * 32 + i0 + r;
    float base = 0.f;
    for (int g = 0; g < 16; ++g) {
      if (g == jg) break;
      base += csum[(i0 + r) * 16 + g];
    }
#pragma unroll
    for (int c = 0; c < 8; ++c)
      Fb[(size_t)(j0 + c) * SLEN + grow] = 1.0f / (base + acc[r][c]);
  }
}

// --- attn writer (8 t/block, LDS E) + amortized fused dense partial-GEMV ---
__global__ __launch_bounds__(256) void attn_kernel(const uint16_t* __restrict__ E,
                                                   const float* __restrict__ Ft,
                                                   const int* __restrict__ idx,
                                                   const float* __restrict__ vp,
                                                   const float* __restrict__ dw,
                                                   float* __restrict__ attn_out,
                                                   float* __restrict__ out) {
  const int h = blockIdx.x;     // 8
  const int tg = blockIdx.y;    // 16 (8 t each)
  const int b = blockIdx.z;     // 4
  const int tid = threadIdx.x;
  const int wave = tid >> 6, lane = tid & 63;
  const int half = lane >> 5, l32 = lane & 31;
  const int bh = b * NHEAD + h;
  __shared__ __align__(16) uint16_t Es[SLEN * SLEN];  // 32 KB: full E tile for (b,h)
  __shared__ int iqs[8][SLEN];
  __shared__ int iks[8][SLEN];
  __shared__ int ivs[8][SLEN];
  __shared__ float Fsl[8][SLEN];
  __shared__ float effs[8][HDIM];
  // stage E: 32 KB = 2048 uint4, coalesced
  {
    const uint4* src = (const uint4*)(E + (size_t)bh * SLEN * SLEN);
    uint4* dst = (uint4*)Es;
#pragma unroll
    for (int i = 0; i < 8; ++i) dst[i * 256 + tid] = src[i * 256 + tid];
  }
  // stage idx rows + F rows for the 8 t values
  {
    const int t0 = tg * 8;
#pragma unroll
    for (int ii = 0; ii < 4; ++ii) {
      int i = ii * 256 + tid;
      int s = i >> 7, j = i & 127;
      int t = t0 + s;
      iqs[s][j] = idx[(0 * SLEN + t) * SLEN + j];
      iks[s][j] = idx[(1 * SLEN + t) * SLEN + j];
      ivs[s][j] = idx[(2 * SLEN + t) * SLEN + j];
      Fsl[s][j] = Ft[((size_t)bh * SLEN + t) * SLEN + j];
    }
  }
  __syncthreads();
  const int k0 = l32 * 4;
  const int d = (wave << 4) + (lane >> 2);   // eff: d-channel for this lane
  const int kg = lane & 3;                   // eff: 4-way k split within 4 lanes
  const float* vb = vp + (size_t)b * SLEN * DMODEL + h * HDIM + d;
  for (int s = 0; s < 8; ++s) {
    const int t = tg * 8 + s;
    const int ikA = iks[s][k0], ikB = iks[s][k0 + 1], ikC = iks[s][k0 + 2], ikD = iks[s][k0 + 3];
    float4 cm;   // causal k-mask for this lane's 4 columns
    cm.x = (k0 + 0 <= t) ? 1.f : 0.f;
    cm.y = (k0 + 1 <= t) ? 1.f : 0.f;
    cm.z = (k0 + 2 <= t) ? 1.f : 0.f;
    cm.w = (k0 + 3 <= t) ? 1.f : 0.f;
    const float inv = 1.0f / (float)(t + 1);
    float* obase = attn_out + ((size_t)((b * SLEN + t) * NHEAD + h)) * SLEN * SLEN;
#pragma unroll 2
    for (int q8 = wave * 2; q8 < SLEN; q8 += 8) {
      const int qe = q8 + half;   // this half-wave's q-row
      f32x4_t val;
      if (qe <= t) {
        const int iq = iqs[s][qe];
        const float f = Fsl[s][iq];
        const uint16_t* Er = Es + iq * SLEN;
        val.x = bf16_to_f32(Er[ikA]) * f * cm.x;
        val.y = bf16_to_f32(Er[ikB]) * f * cm.y;
        val.z = bf16_to_f32(Er[ikC]) * f * cm.z;
        val.w = bf16_to_f32(Er[ikD]) * f * cm.w;
      } else {
        val.x = inv * cm.x; val.y = inv * cm.y;
        val.z = inv * cm.z; val.w = inv * cm.w;
      }
      __builtin_nontemporal_store(val, (f32x4_t*)(obase + (size_t)qe * SLEN + k0));
    }
    // effs[s][d] = F[t][t] * sum_{k<=t} E[t][ik[k]] * vp[b, iv[k], h*64+d]
    // 8-deep batched prefetch; per-lane summation order (k ascending) preserved.
    {
      const uint16_t* Et = Es + t * SLEN;
      float acc = 0.f;
      int k = kg;
      for (; k + 28 <= t; k += 32) {
        float vv[8], ee[8];
#pragma unroll
        for (int i = 0; i < 8; ++i) {
          vv[i] = vb[(size_t)ivs[s][k + 4 * i] * DMODEL];
          ee[i] = bf16_to_f32(Et[iks[s][k + 4 * i]]);
        }
#pragma unroll
        for (int i = 0; i < 8; ++i) acc += ee[i] * vv[i];
      }
      for (; k <= t; k += 4)
        acc += bf16_to_f32(Et[iks[s][k]]) * vb[(size_t)ivs[s][k] * DMODEL];
      acc += __shfl_xor(acc, 1);
      acc += __shfl_xor(acc, 2);
      if (kg == 0) effs[s][d] = acc * Fsl[s][t];
    }
  }
  __syncthreads();
  // out[b,t0+s,c] += sum_d effs[s][d] * dw[h*64+d][c]; dw slice read ONCE/block.
  {
    const int c0 = tid * 2;
    const float* wb = dw + (size_t)(h * HDIM) * DMODEL + c0;
    float s0[8] = {}, s1[8] = {};
#pragma unroll 8
    for (int dd = 0; dd < HDIM; ++dd) {
      const float2 wv = *(const float2*)(wb + (size_t)dd * DMODEL);
#pragma unroll
      for (int s = 0; s < 8; ++s) {
        const float e = effs[s][dd];
        s0[s] += e * wv.x;
        s1[s] += e * wv.y;
      }
    }
    const int t0 = tg * 8;
#pragma unroll
    for (int s = 0; s < 8; ++s) {
      float* orow = out + ((size_t)(b * SLEN + t0 + s)) * DMODEL;
      atomicAdd(orow + c0 + 0, s0[s]);
      atomicAdd(orow + c0 + 1, s1[s]);
    }
  }
}

extern "C" void kernel_launch(void* const* d_in, const int* in_sizes, int n_in,
                              void* d_out, int out_size, void* d_ws, size_t ws_size,
                              hipStream_t stream) {
  const float* q    = (const float*)d_in[0];
  const float* k    = (const float*)d_in[1];
  const float* v    = (const float*)d_in[2];
  const float* wq_w = (const float*)d_in[4];
  const float* wq_b = (const float*)d_in[5];
  const float* wk_w = (const float*)d_in[6];
  const float* wk_b = (const float*)d_in[7];
  const float* wv_w = (const float*)d_in[8];
  const float* wv_b = (const float*)d_in[9];
  const float* dw   = (const float*)d_in[10];
  const float* db   = (const float*)d_in[11];

  float* out  = (float*)d_out;          // 4*128*512
  float* attn = out + 262144;           // 4*128*8*128*128

  // ws layout (float slots): E(bf16) | idx | qp | kp | vp | Ft
  float* wsf = (float*)d_ws;
  uint16_t* E = (uint16_t*)wsf;                    // 524288 u16 in 262144 float slots
  int*   idx = (int*)(wsf + 262144);               // 49152
  float* qp  = wsf + 311296;
  float* kp  = qp + 262144;
  float* vp  = kp + 262144;
  float* Ft  = vp + 262144;                        // 524288
  (void)in_sizes; (void)n_in; (void)out_size; (void)ws_size;

  out_init_kernel<<<dim3(512, 1, 1), 512, 0, stream>>>(out, db);
  idx_kernel<<<dim3(3, 128, 1), 128, 0, stream>>>(idx);
  proj_kernel<<<dim3(8, 16, 3), 256, 0, stream>>>(q, k, v, wq_w, wk_w, wv_w,
                                                  wq_b, wk_b, wv_b, qp, kp, vp);
  sef_kernel<<<dim3(8, 4, 4), 256, 0, stream>>>(qp, kp, E, Ft);
  attn_kernel<<<dim3(8, 16, 4), 256, 0, stream>>>(E, Ft, idx, vp, dw, attn, out);
}